// Round 2
// baseline (702.894 us; speedup 1.0000x reference)
//
#include <hip/hip_runtime.h>
#include <hip/hip_bf16.h>

using bf16x8 = __attribute__((ext_vector_type(8))) __bf16;
using f32x4  = __attribute__((ext_vector_type(4))) float;
typedef unsigned short ushort8v __attribute__((ext_vector_type(8)));
typedef unsigned short ushort4v __attribute__((ext_vector_type(4)));

#define B_ 4
#define C_ 128
#define F_ 128
#define T_ 512
#define H_ 256
#define FT_ 65536
#define M_ 262144

static __device__ __forceinline__ unsigned short bf16bits(float f) {
    __hip_bfloat16 h = __float2bfloat16(f);
    return *(unsigned short*)&h;
}

static __device__ __forceinline__ f32x4 ld4(const __hip_bfloat16* p) {
    ushort4v u = *(const ushort4v*)p;
    f32x4 r;
#pragma unroll
    for (int i = 0; i < 4; ++i) {
        union { unsigned int ui; float f; } cv;
        cv.ui = ((unsigned int)u[i]) << 16;
        r[i] = cv.f;
    }
    return r;
}

static __device__ __forceinline__ f32x4 zero4() {
    f32x4 r = {0.f, 0.f, 0.f, 0.f};
    return r;
}

// ---------------- K0: cast weights to bf16 ----------------
__global__ __launch_bounds__(256) void k_cast(const float* __restrict__ w_in,
                                              const float* __restrict__ w_out,
                                              __hip_bfloat16* __restrict__ wib,
                                              __hip_bfloat16* __restrict__ wob) {
    int i = blockIdx.x * 256 + threadIdx.x;
    if (i < 512 * 128) wib[i] = __float2bfloat16(w_in[i]);
    if (i < 128 * 256) wob[i] = __float2bfloat16(w_out[i]);
}

// ---------------- K1: RMSNorm + transpose to (M, C) bf16 ----------------
__global__ __launch_bounds__(256) void k_rms(const float* __restrict__ x,
                                             const float* __restrict__ gn,
                                             __hip_bfloat16* __restrict__ yt) {
    __shared__ float xs[128][129];
    __shared__ float ssqs[2][128];
    __shared__ float scl[128];
    const int bid = blockIdx.x;
    const int tc = bid & 3;
    const int bf = bid >> 2;              // b*F + f
    const int b = bf >> 7, f = bf & 127;
    const int t0 = tc * 128;
    const int th = threadIdx.x;
    const int tl = th & 127, ch = th >> 7;
    const size_t base = (size_t)b * (C_ * FT_) + (size_t)f * T_ + t0;
    float ssq = 0.f;
    for (int c = ch; c < 128; c += 2) {
        float v = x[base + (size_t)c * FT_ + tl];
        xs[c][tl] = v;
        ssq += v * v;
    }
    ssqs[ch][tl] = ssq;
    __syncthreads();
    if (th < 128) {
        float ms = (ssqs[0][th] + ssqs[1][th]) * (1.f / 128.f);
        scl[th] = rsqrtf(ms + 1e-6f);
    }
    __syncthreads();
    const int c = th & 127, tp = th >> 7;
    const float gc = gn[c];
    const size_t m0 = (size_t)bf * T_ + t0;
    for (int tt = 0; tt < 128; tt += 2) {
        const int t = tt + tp;
        float v = xs[c][t] * scl[t] * gc;
        yt[(m0 + t) * 128 + c] = __float2bfloat16(v);
    }
}

// ---------------- K2: GEMM1 (M x 512, K=128) + bias + GLU -> g (M x 256), LDS-free ----------------
// grid = (4 n-blocks, M/128).  MFMA fragments loaded directly from global:
// per (frag,kk) a quarter-wave reads 16 full 64B lines (row bytes kk*64..+63).
// B-rows use the GLU interleave: na even -> a-channel, na odd -> b-channel, so
// GLU pairing is same-lane same-reg.
__global__ __launch_bounds__(256) void k_gemm1(const __hip_bfloat16* __restrict__ yt,
                                               const __hip_bfloat16* __restrict__ wib,
                                               const float* __restrict__ b_in,
                                               __hip_bfloat16* __restrict__ gbuf) {
    __shared__ __hip_bfloat16 gl[128][68];
    const int hb = blockIdx.x * 64;
    const int m0 = blockIdx.y * 128;
    const int th = threadIdx.x;
    const int lane = th & 63, wave = th >> 6;
    const int wm = wave >> 1, wn = wave & 1;
    const int lr = lane & 15, lg = lane >> 4;
    const unsigned short* ytu = (const unsigned short*)yt;
    const unsigned short* wibu = (const unsigned short*)wib;
    f32x4 acc[4][4] = {};
#pragma unroll
    for (int kk = 0; kk < 4; ++kk) {
        bf16x8 af[4], bq[4];
#pragma unroll
        for (int ma = 0; ma < 4; ++ma) {
            const int row = m0 + wm * 64 + ma * 16 + lr;
            af[ma] = *(const bf16x8*)(ytu + (size_t)row * 128 + kk * 32 + lg * 8);
        }
#pragma unroll
        for (int na = 0; na < 4; ++na) {
            const int q = wn * 2 + (na >> 1);
            const int o = ((na & 1) ? 256 : 0) + hb + q * 16 + lr;
            bq[na] = *(const bf16x8*)(wibu + (size_t)o * 128 + kk * 32 + lg * 8);
        }
#pragma unroll
        for (int ma = 0; ma < 4; ++ma)
#pragma unroll
            for (int na = 0; na < 4; ++na)
                acc[ma][na] = __builtin_amdgcn_mfma_f32_16x16x32_bf16(af[ma], bq[na], acc[ma][na], 0, 0, 0);
    }
    // GLU -> stage 128x64 bf16 tile in LDS, then coalesced global write
#pragma unroll
    for (int p = 0; p < 2; ++p) {
        const int q = wn * 2 + p;
        const int oa = hb + q * 16 + lr;
        const float ba = b_in[oa];
        const float bb = b_in[256 + oa];
#pragma unroll
        for (int ma = 0; ma < 4; ++ma) {
            f32x4 va = acc[ma][2 * p];
            f32x4 vb = acc[ma][2 * p + 1];
#pragma unroll
            for (int j = 0; j < 4; ++j) {
                float aa = va[j] + ba;
                float bv = vb[j] + bb;
                float gv = aa / (1.f + __expf(-bv));
                gl[wm * 64 + ma * 16 + lg * 4 + j][wn * 32 + p * 16 + lr] = __float2bfloat16(gv);
            }
        }
    }
    __syncthreads();
#pragma unroll
    for (int pass = 0; pass < 8; ++pass) {
        const int ml = pass * 16 + (th >> 4);
        const int h4 = (th & 15) * 4;
        ushort4v v = *(const ushort4v*)(&gl[ml][h4]);
        *(ushort4v*)((unsigned short*)gbuf + (size_t)(m0 + ml) * 256 + hb + h4) = v;
    }
}

// ---------------- K2.5: depthwise 3x3 (causal T, same F) + bias + SiLU ----------------
// Pure streaming, no LDS. 2048 blocks (XCD-chunked), 256 threads.
// Thread: 4 channels x 32 t sliding window. 512B-coalesced loads/stores per t-row.
__global__ __launch_bounds__(256) void k_dw(const __hip_bfloat16* __restrict__ g,
                                            const float* __restrict__ w_dw,
                                            const float* __restrict__ b_dw,
                                            __hip_bfloat16* __restrict__ s) {
    const int orig = ((blockIdx.x & 7) << 8) + (blockIdx.x >> 3);  // XCD-chunked swizzle (2048 = 8*256)
    const int bf = orig >> 2, tc = orig & 3;
    const int f = bf & 127;
    const int th = threadIdx.x;
    const int o4 = (th & 63) << 2;
    const int tb = tc * 128 + (th >> 6) * 32;
    const bool hm = (f > 0), hp = (f < 127);
    const __hip_bfloat16* gc_ = g + (size_t)bf * 512 * 256;
    const __hip_bfloat16* gm_ = gc_ - (size_t)512 * 256;
    const __hip_bfloat16* gp_ = gc_ + (size_t)512 * 256;
    f32x4 wv[9], bias;
#pragma unroll
    for (int i = 0; i < 9; ++i)
#pragma unroll
        for (int c = 0; c < 4; ++c) wv[i][c] = w_dw[(o4 + c) * 9 + i];
#pragma unroll
    for (int c = 0; c < 4; ++c) bias[c] = b_dw[o4 + c];
    f32x4 a0[3], a1[3], a2[3];
#pragma unroll
    for (int kI = 0; kI < 2; ++kI) {
        const int t = tb - 2 + kI;
        const bool tv = (t >= 0);
        const size_t off = (size_t)t * 256 + o4;
        a0[kI] = (tv && hm) ? ld4(gm_ + off) : zero4();
        a1[kI] = tv        ? ld4(gc_ + off) : zero4();
        a2[kI] = (tv && hp) ? ld4(gp_ + off) : zero4();
    }
    unsigned short* su = (unsigned short*)s;
#pragma unroll 4
    for (int k = 0; k < 32; ++k) {
        const int t = tb + k;
        const size_t off = (size_t)t * 256 + o4;
        a0[2] = hm ? ld4(gm_ + off) : zero4();
        a1[2] = ld4(gc_ + off);
        a2[2] = hp ? ld4(gp_ + off) : zero4();
        f32x4 av = bias;
#pragma unroll
        for (int j = 0; j < 3; ++j) {
            av += wv[j] * a0[j];
            av += wv[3 + j] * a1[j];
            av += wv[6 + j] * a2[j];
        }
        ushort4v uo;
#pragma unroll
        for (int c = 0; c < 4; ++c) {
            float d = 1.f + __expf(-av[c]);
            uo[c] = bf16bits(av[c] * __builtin_amdgcn_rcpf(d));
        }
        *(ushort4v*)(su + ((size_t)bf * 512 + t) * 256 + o4) = uo;
        a0[0] = a0[1]; a0[1] = a0[2];
        a1[0] = a1[1]; a1[1] = a1[2];
        a2[0] = a2[1]; a2[1] = a2[2];
    }
}

// ---------------- K3: GEMM2 (C x M, K=256) + bias + residual, LDS-free ----------------
// Operand-swapped: D[c][m] so stores are t-contiguous per 16 lanes.
__global__ __launch_bounds__(256) void k_gemm2(const __hip_bfloat16* __restrict__ s,
                                               const __hip_bfloat16* __restrict__ wob,
                                               const float* __restrict__ b_out,
                                               const float* __restrict__ x,
                                               float* __restrict__ out) {
    const int m0 = blockIdx.x * 128;
    const int th = threadIdx.x;
    const int lane = th & 63, wave = th >> 6;
    const int wc = wave >> 1, wn = wave & 1;
    const int lr = lane & 15, lg = lane >> 4;
    const unsigned short* su = (const unsigned short*)s;
    const unsigned short* wu = (const unsigned short*)wob;
    f32x4 acc[4][4] = {};
#pragma unroll
    for (int kk = 0; kk < 8; ++kk) {
        bf16x8 af[4], bq[4];
#pragma unroll
        for (int ca = 0; ca < 4; ++ca) {
            const int row = wc * 64 + ca * 16 + lr;
            af[ca] = *(const bf16x8*)(wu + (size_t)row * 256 + kk * 32 + lg * 8);
        }
#pragma unroll
        for (int na = 0; na < 4; ++na) {
            const int m = m0 + wn * 64 + na * 16 + lr;
            bq[na] = *(const bf16x8*)(su + (size_t)m * 256 + kk * 32 + lg * 8);
        }
#pragma unroll
        for (int ca = 0; ca < 4; ++ca)
#pragma unroll
            for (int na = 0; na < 4; ++na)
                acc[ca][na] = __builtin_amdgcn_mfma_f32_16x16x32_bf16(af[ca], bq[na], acc[ca][na], 0, 0, 0);
    }
    // epilogue: out[b,c,f,t] = D[c][m] + b_out[c] + x
    const size_t sbase = (size_t)(m0 >> 16) * (C_ * FT_);
#pragma unroll
    for (int ca = 0; ca < 4; ++ca) {
        const int cbase = wc * 64 + ca * 16 + lg * 4;
#pragma unroll
        for (int na = 0; na < 4; ++na) {
            const int m = m0 + wn * 64 + na * 16 + lr;
            const size_t sp = sbase + (size_t)(m & 65535);
#pragma unroll
            for (int j = 0; j < 4; ++j) {
                const int cc = cbase + j;
                const size_t idx = sp + (size_t)cc * FT_;
                out[idx] = acc[ca][na][j] + b_out[cc] + x[idx];
            }
        }
    }
}

extern "C" void kernel_launch(void* const* d_in, const int* in_sizes, int n_in,
                              void* d_out, int out_size, void* d_ws, size_t ws_size,
                              hipStream_t stream) {
    const float* x      = (const float*)d_in[0];
    const float* g_norm = (const float*)d_in[1];
    const float* w_in   = (const float*)d_in[2];
    const float* b_in   = (const float*)d_in[3];
    const float* w_dw   = (const float*)d_in[4];
    const float* b_dw   = (const float*)d_in[5];
    const float* w_out  = (const float*)d_in[6];
    const float* b_out  = (const float*)d_in[7];
    float* out = (float*)d_out;

    // workspace layout (~256.2 MB):
    //   [0, 128MB)        g    : GLU output, (M,256) bf16
    //   [128MB, 256MB)    s    : dwconv+SiLU output, (M,256) bf16
    //   [192MB, 256MB)    y_t  : rmsnorm output (M,128) bf16 — aliases s's upper
    //                            half; dead before k_dw writes s.
    //   [256MB, +192KB)   bf16 weights
    char* ws = (char*)d_ws;
    __hip_bfloat16* gbuf = (__hip_bfloat16*)ws;
    __hip_bfloat16* sbuf = (__hip_bfloat16*)(ws + (size_t)134217728);
    __hip_bfloat16* ybuf = (__hip_bfloat16*)(ws + (size_t)134217728 + 67108864);
    __hip_bfloat16* wib  = (__hip_bfloat16*)(ws + (size_t)268435456);
    __hip_bfloat16* wob  = wib + 512 * 128;

    k_cast<<<dim3(256), dim3(256), 0, stream>>>(w_in, w_out, wib, wob);
    k_rms<<<dim3(2048), dim3(256), 0, stream>>>(x, g_norm, ybuf);
    k_gemm1<<<dim3(4, 2048), dim3(256), 0, stream>>>(ybuf, wib, b_in, gbuf);
    k_dw<<<dim3(2048), dim3(256), 0, stream>>>(gbuf, w_dw, b_dw, sbuf);
    k_gemm2<<<dim3(2048), dim3(256), 0, stream>>>(sbuf, wob, b_out, x, out);
}